// Round 11
// baseline (228.512 us; speedup 1.0000x reference)
//
#include <hip/hip_runtime.h>
#include <hip/hip_cooperative_groups.h>

namespace cg = cooperative_groups;

// out[b,v] = dot(OT[b, pid[v], :], W[v, :]) + bias[v]
// B=32, Q=180, H=768, V=19004. fp32 in/out, bf16 MFMA inside.
#define BB 32
#define QQ 180
#define HH 768
#define VV 19004
#define VB 64
#define KQ 192       // K per quarter (K-split x4 -> 4*nt ~ 1496 items)
#define SB 19008     // res stride (pos dim)
#define ST 200       // OT LDS row stride in bf16 elems (192 + 8 pad)

// ws layout (bytes)
#define WS_CUR    0        // 256 ints (scatter cursors)
#define WS_NTOT   1024     // 1 int
#define WS_DESC   2048     // 512 int4 (8192 B)
#define WS_SORTED 10240    // VV ints (76016 B)
#define WS_POSOF  86272    // VV ints
#define WS_RES    162304   // 4 * 32 * 19008 * 4 = 9,732,096 B

typedef __attribute__((ext_vector_type(8))) short short8v;  // 8 bf16
typedef __attribute__((ext_vector_type(4))) float f32x4;

__device__ __forceinline__ short f2bf(float f) {  // RNE fp32->bf16
    unsigned u = __builtin_bit_cast(unsigned, f);
    u += 0x7FFFu + ((u >> 16) & 1u);
    return (short)(u >> 16);
}

// ONE cooperative kernel: hist/scan/desc -> scatter -> MFMA main -> combine.
// Main phase per item (chunk ci = item>>2, K-quarter kh = item&3), R7 shape:
// stage OT quarter to LDS bf16, one-shot 12-float4 W burst issued BEFORE the
// barrier, 6 K-steps x 2 MFMA from LDS A-frags, full-line pos-space stores.
__launch_bounds__(256, 3)
__global__ void mono_k(const float* __restrict__ OT, const float* __restrict__ W,
                       const float* __restrict__ bias, const int* __restrict__ pid,
                       float* __restrict__ out, int* __restrict__ cur,
                       int* __restrict__ ntot, int4* __restrict__ desc,
                       int* __restrict__ sorted, int* __restrict__ posOf,
                       float* __restrict__ res) {
    cg::grid_group grid = cg::this_grid();
    const int bid = blockIdx.x;
    const int tid = threadIdx.x;
    const int nblk = gridDim.x;

    __shared__ int h[256];
    __shared__ int s1[256];
    __shared__ short OTlds[BB * ST];  // 12,800 B

    // ---- phase 0 (block 0 solo): histogram + scan + desc + cursors ----
    if (bid == 0) {
        h[tid] = 0;
        __syncthreads();
        for (int v = tid; v < VV; v += 256) atomicAdd(&h[pid[v]], 1);
        __syncthreads();
        const int c = h[tid];
        s1[tid] = c;
        __syncthreads();
        for (int off = 1; off < 256; off <<= 1) {
            int a = (tid >= off) ? s1[tid - off] : 0;
            __syncthreads();
            s1[tid] += a;
            __syncthreads();
        }
        const int start = s1[tid] - c;   // exclusive prefix
        cur[tid] = start;
        const int nch = (c + VB - 1) / VB;
        __syncthreads();
        h[tid] = nch;
        __syncthreads();
        for (int off = 1; off < 256; off <<= 1) {
            int a = (tid >= off) ? h[tid - off] : 0;
            __syncthreads();
            h[tid] += a;
            __syncthreads();
        }
        if (tid < QQ) {
            const int cb = h[tid] - nch;
            for (int j = 0; j < nch; ++j)
                desc[cb + j] = make_int4(tid, start + j * VB, min(VB, c - j * VB), 0);
        }
        if (tid == 255) *ntot = h[255];
    }
    grid.sync();

    // ---- phase 1: parallel scatter (bucket order irrelevant; posOf consistent)
    for (int v = bid * 256 + tid; v < VV; v += nblk * 256) {
        const int q = pid[v];
        const int pos = atomicAdd(&cur[q], 1);
        sorted[pos] = v;
        posOf[v] = pos;
    }
    grid.sync();

    // ---- phase 2: main (block-stride over 4*nt items) ----
    const int nitems = 4 * (*ntot);
    const int lane = tid & 63;
    const int w = tid >> 6;           // v-tile (4 waves x 16 v)
    const int co = lane & 15;         // frag row/col index
    const int kq = lane >> 4;         // k-octet
    const int pl = 16 * w + co;       // pos-local in chunk

    for (int item = bid; item < nitems; item += nblk) {
        const int4 d = desc[item >> 2];
        const int kh = item & 3;
        const int q     = __builtin_amdgcn_readfirstlane(d.x);
        const int start = __builtin_amdgcn_readfirstlane(d.y);
        const int len   = __builtin_amdgcn_readfirstlane(d.z);

        __syncthreads();  // previous item's LDS readers done
        {   // stage OT[0..31][q][kh*192 .. +192) as bf16
            const int r = tid >> 3;
            const int o = tid & 7;
            const float* src = OT + ((size_t)r * QQ + q) * HH + kh * KQ + o * 8;
            short* dst = &OTlds[r * ST + o * 8];
#pragma unroll
            for (int it = 0; it < 3; ++it) {
                const float4 f0 = *(const float4*)(src + it * 64);
                const float4 f1 = *(const float4*)(src + it * 64 + 4);
                short8v s;
                s[0]=f2bf(f0.x); s[1]=f2bf(f0.y); s[2]=f2bf(f0.z); s[3]=f2bf(f0.w);
                s[4]=f2bf(f1.x); s[5]=f2bf(f1.y); s[6]=f2bf(f1.z); s[7]=f2bf(f1.w);
                *(short8v*)(dst + it * 64) = s;
            }
        }
        // one-shot W burst issued before the barrier (overlaps staging drain)
        const int vg = sorted[start + min(pl, len - 1)];
        const float4* wp4 = (const float4*)(W + (size_t)vg * HH + kh * KQ + kq * 8);
        float4 wf[12];
#pragma unroll
        for (int kk = 0; kk < 6; ++kk) {
            wf[2 * kk]     = wp4[kk * 8];
            wf[2 * kk + 1] = wp4[kk * 8 + 1];
        }
        __syncthreads();

        f32x4 acc0 = {0.f, 0.f, 0.f, 0.f};
        f32x4 acc1 = {0.f, 0.f, 0.f, 0.f};
#pragma unroll
        for (int kk = 0; kk < 6; ++kk) {
            const float4 wf0 = wf[2 * kk];
            const float4 wf1 = wf[2 * kk + 1];
            short8v bf;
            bf[0]=f2bf(wf0.x); bf[1]=f2bf(wf0.y); bf[2]=f2bf(wf0.z); bf[3]=f2bf(wf0.w);
            bf[4]=f2bf(wf1.x); bf[5]=f2bf(wf1.y); bf[6]=f2bf(wf1.z); bf[7]=f2bf(wf1.w);
            const short8v a0v = *(const short8v*)&OTlds[co * ST + kq * 8 + kk * 32];
            const short8v a1v = *(const short8v*)&OTlds[(16 + co) * ST + kq * 8 + kk * 32];
            acc0 = __builtin_amdgcn_mfma_f32_16x16x32_bf16(a0v, bf, acc0, 0, 0, 0);
            acc1 = __builtin_amdgcn_mfma_f32_16x16x32_bf16(a1v, bf, acc1, 0, 0, 0);
        }
        // C[row=b][col=v]: row = kq*4+reg, col = co (m89-verified, R7-proven)
        if (pl < len) {
            float* rp = res + (size_t)(kh * BB) * SB + start + pl;
#pragma unroll
            for (int r2 = 0; r2 < 4; ++r2) {
                rp[(size_t)(kq * 4 + r2) * SB]      = acc0[r2];
                rp[(size_t)(16 + kq * 4 + r2) * SB] = acc1[r2];
            }
        }
    }
    grid.sync();

    // ---- phase 3: combine (coalesced out writes, L2 gathers) ----
    for (int idx = bid * 256 + tid; idx < BB * VV; idx += nblk * 256) {
        const int b = (int)((unsigned)idx / VV);
        const int v = idx - b * VV;
        const int pos = posOf[v];
        const float s = res[(size_t)b * SB + pos]
                      + res[(size_t)(BB + b) * SB + pos]
                      + res[(size_t)(2 * BB + b) * SB + pos]
                      + res[(size_t)(3 * BB + b) * SB + pos];
        out[(size_t)b * VV + v] = s + bias[v];
    }
}

extern "C" void kernel_launch(void* const* d_in, const int* in_sizes, int n_in,
                              void* d_out, int out_size, void* d_ws, size_t ws_size,
                              hipStream_t stream) {
    const float* OT   = (const float*)d_in[0];  // [B,Q,H]
    const float* W    = (const float*)d_in[1];  // [V,H]
    const float* bias = (const float*)d_in[2];  // [V]
    const int*   pid  = (const int*)d_in[3];    // [V]
    float* out = (float*)d_out;                 // [B,V]

    char* ws = (char*)d_ws;
    int*   cur    = (int*)(ws + WS_CUR);
    int*   ntot   = (int*)(ws + WS_NTOT);
    int4*  desc   = (int4*)(ws + WS_DESC);
    int*   sorted = (int*)(ws + WS_SORTED);
    int*   posOf  = (int*)(ws + WS_POSOF);
    float* res    = (float*)(ws + WS_RES);

    int maxb = 0;
    if (hipOccupancyMaxActiveBlocksPerMultiprocessor(&maxb, mono_k, 256, 0)
            != hipSuccess || maxb < 1)
        maxb = 2;  // conservative fallback
    int nblk = maxb * 256;
    if (nblk > 1496) nblk = 1496;

    void* args[] = {(void*)&OT, (void*)&W, (void*)&bias, (void*)&pid, (void*)&out,
                    (void*)&cur, (void*)&ntot, (void*)&desc, (void*)&sorted,
                    (void*)&posOf, (void*)&res};
    hipLaunchCooperativeKernel(mono_k, dim3(nblk), dim3(256), args, 0, stream);
}

// Round 12
// 45.073 us; speedup vs baseline: 5.0699x; 5.0699x over previous
//
#include <hip/hip_runtime.h>
#include <hip/hip_bf16.h>

// out[b,v] = dot(OT[b, pid[v], :], W[v, :]) + bias[v]
// B=32, Q=180, H=768, V=19004. fp32 in/out, bf16 MFMA inside.
#define BB 32
#define QQ 180
#define HH 768
#define VV 19004
#define VB 64
#define KH 384       // K per half
#define SB 19008     // res stride (pos dim)
#define MAXDESC 480
#define STRIDE 392   // OT LDS row stride in bf16 elems (384 + 8 pad)
#define NB 80        // prep blocks
#define CH 238       // v's per prep block (80*238 = 19040 >= VV)

// ws layout (bytes)
#define WS_H      0        // NB*QQ ints = 57600
#define WS_BASE   65536    // NB*QQ ints = 57600
#define WS_NTOT   131072   // 1 int
#define WS_DESC   132096   // 480 int4 = 7680
#define WS_SORTED 140288   // VV ints = 76016
#define WS_POSOF  217088   // VV ints = 76016
#define WS_RES    294912   // 2 * 32 * 19008 * 4 = 4,866,048

typedef __attribute__((ext_vector_type(8))) short short8v;  // 8 bf16 (4 VGPR)
typedef __attribute__((ext_vector_type(4))) float f32x4;

__device__ __forceinline__ short f2bf(float f) {  // RNE fp32->bf16
    unsigned u = __builtin_bit_cast(unsigned, f);
    u += 0x7FFFu + ((u >> 16) & 1u);
    return (short)(u >> 16);
}

// ---------- prep 1: per-block LDS histograms (no atomic contention) ----------
__global__ void hist_k(const int* __restrict__ pid, int* __restrict__ h) {
    __shared__ int lc[QQ];
    const int t = threadIdx.x, b = blockIdx.x;
    if (t < QQ) lc[t] = 0;
    __syncthreads();
    const int v = b * CH + t;
    if (t < CH && v < VV) atomicAdd(&lc[pid[v]], 1);
    __syncthreads();
    if (t < QQ) h[b * QQ + t] = lc[t];
}

// ---------- prep 2: column-sum + q-scan + desc + per-(blk,q) scatter bases ----
__global__ void scan_k(const int* __restrict__ h, int* __restrict__ base,
                       int4* __restrict__ desc, int* __restrict__ ntot) {
    __shared__ int s1[256];
    __shared__ int s2[256];
    const int t = threadIdx.x;
    int c = 0;
    if (t < QQ)
        for (int i = 0; i < NB; ++i) c += h[i * QQ + t];
    s1[t] = c;
    __syncthreads();
    for (int off = 1; off < 256; off <<= 1) {
        int a = (t >= off) ? s1[t - off] : 0;
        __syncthreads();
        s1[t] += a;
        __syncthreads();
    }
    const int qs = s1[t] - c;              // exclusive prefix over q
    const int nch = (c + VB - 1) / VB;
    s2[t] = nch;
    __syncthreads();
    for (int off = 1; off < 256; off <<= 1) {
        int a = (t >= off) ? s2[t - off] : 0;
        __syncthreads();
        s2[t] += a;
        __syncthreads();
    }
    if (t < QQ) {
        const int cb = s2[t] - nch;
        for (int j = 0; j < nch; ++j)
            desc[cb + j] = make_int4(t, qs + j * VB, min(VB, c - j * VB), 0);
        int run = qs;                       // per-block scatter bases
        for (int i = 0; i < NB; ++i) {
            base[i * QQ + t] = run;
            run += h[i * QQ + t];
        }
    }
    if (t == 255) *ntot = s2[255];
}

// ---------- prep 3: scatter via per-block LDS cursors (no global atomics) ----
__global__ void scatter_k(const int* __restrict__ pid, const int* __restrict__ base,
                          int* __restrict__ sorted, int* __restrict__ posOf) {
    __shared__ int cur[QQ];
    const int t = threadIdx.x, b = blockIdx.x;
    if (t < QQ) cur[t] = base[b * QQ + t];
    __syncthreads();
    const int v = b * CH + t;
    if (t < CH && v < VV) {
        const int q = pid[v];
        const int pos = atomicAdd(&cur[q], 1);   // LDS, 180 counters, 1 block
        sorted[pos] = v;
        posOf[v] = pos;
    }
}

// ---------- main: MFMA 16x16x32 bf16, block = (chunk, K-half) — R7 verbatim --
__launch_bounds__(256)
__global__ void main_k(const float* __restrict__ OT, const float* __restrict__ W,
                       const int* __restrict__ sorted, const int4* __restrict__ desc,
                       const int* __restrict__ ntot, float* __restrict__ res) {
    const int nt = *ntot;
    const int bid = blockIdx.x;
    const int ci = bid >> 1;
    if (ci >= nt) return;
    const int kh = bid & 1;
    const int4 d = desc[ci];
    const int q     = __builtin_amdgcn_readfirstlane(d.x);
    const int start = __builtin_amdgcn_readfirstlane(d.y);
    const int len   = __builtin_amdgcn_readfirstlane(d.z);
    const int tid = threadIdx.x;

    __shared__ short OTlds[BB * STRIDE];  // 25,088 B

    // stage OT[0..31][q][kh*384 .. +384) as bf16 (coalesced fp32 reads)
    {
        const int r = tid >> 3;   // b row 0..31
        const int o = tid & 7;    // octet
        const float* src = OT + ((size_t)r * QQ + q) * HH + kh * KH + o * 8;
        short* dst = &OTlds[r * STRIDE + o * 8];
#pragma unroll
        for (int it = 0; it < 6; ++it) {
            const float4 f0 = *(const float4*)(src + it * 64);
            const float4 f1 = *(const float4*)(src + it * 64 + 4);
            short8v s;
            s[0] = f2bf(f0.x); s[1] = f2bf(f0.y); s[2] = f2bf(f0.z); s[3] = f2bf(f0.w);
            s[4] = f2bf(f1.x); s[5] = f2bf(f1.y); s[6] = f2bf(f1.z); s[7] = f2bf(f1.w);
            *(short8v*)(dst + it * 64) = s;
        }
    }

    const int lane = tid & 63;
    const int w = tid >> 6;           // v-tile
    const int co = lane & 15;         // frag col
    const int kq = lane >> 4;         // k-quad
    const int vl = 16 * w + co;       // v-local in chunk
    const int vg = sorted[start + min(vl, len - 1)];
    const float4* wp4 = (const float4*)(W + (size_t)vg * HH + kh * KH + kq * 8);
    const short* a0 = &OTlds[co * STRIDE + kq * 8];

    // burst: issue ALL W loads before any use (24 outstanding 16B/lane)
    float4 wf[24];
#pragma unroll
    for (int kk = 0; kk < 12; ++kk) {
        wf[2 * kk]     = wp4[kk * 8];
        wf[2 * kk + 1] = wp4[kk * 8 + 1];
    }

    __syncthreads();

    f32x4 acc0 = {0.f, 0.f, 0.f, 0.f};
    f32x4 acc1 = {0.f, 0.f, 0.f, 0.f};
#pragma unroll
    for (int kk = 0; kk < 12; ++kk) {
        const float4 wf0 = wf[2 * kk];
        const float4 wf1 = wf[2 * kk + 1];
        short8v bf;
        bf[0] = f2bf(wf0.x); bf[1] = f2bf(wf0.y); bf[2] = f2bf(wf0.z); bf[3] = f2bf(wf0.w);
        bf[4] = f2bf(wf1.x); bf[5] = f2bf(wf1.y); bf[6] = f2bf(wf1.z); bf[7] = f2bf(wf1.w);
        const short8v a0v = *(const short8v*)(a0 + kk * 32);
        const short8v a1v = *(const short8v*)(a0 + 16 * STRIDE + kk * 32);
        acc0 = __builtin_amdgcn_mfma_f32_16x16x32_bf16(a0v, bf, acc0, 0, 0, 0);
        acc1 = __builtin_amdgcn_mfma_f32_16x16x32_bf16(a1v, bf, acc1, 0, 0, 0);
    }

    // C[row=b][col=v]: row = (lane>>4)*4 + reg, col = lane&15  (m89-verified)
    if (vl < len) {
        float* rp = res + (size_t)(kh * BB) * SB + start + vl;
#pragma unroll
        for (int r2 = 0; r2 < 4; ++r2) {
            rp[(size_t)(kq * 4 + r2) * SB]      = acc0[r2];
            rp[(size_t)(16 + kq * 4 + r2) * SB] = acc1[r2];
        }
    }
}

// ---------- combine: gather res via posOf (L2), coalesced out writes ----------
__global__ void combine_k(const float* __restrict__ res, const int* __restrict__ posOf,
                          const float* __restrict__ bias, float* __restrict__ out) {
    const int v = blockIdx.x * 256 + threadIdx.x;
    if (v >= VV) return;
    const int b = blockIdx.y;
    const int pos = posOf[v];
    const float s = res[(size_t)b * SB + pos] + res[(size_t)(BB + b) * SB + pos];
    out[(size_t)b * VV + v] = s + bias[v];
}

extern "C" void kernel_launch(void* const* d_in, const int* in_sizes, int n_in,
                              void* d_out, int out_size, void* d_ws, size_t ws_size,
                              hipStream_t stream) {
    const float* OT   = (const float*)d_in[0];  // [B,Q,H]
    const float* W    = (const float*)d_in[1];  // [V,H]
    const float* bias = (const float*)d_in[2];  // [V]
    const int*   pid  = (const int*)d_in[3];    // [V]
    float* out = (float*)d_out;                 // [B,V]

    char* ws = (char*)d_ws;
    int*   h      = (int*)(ws + WS_H);
    int*   base   = (int*)(ws + WS_BASE);
    int*   ntot   = (int*)(ws + WS_NTOT);
    int4*  desc   = (int4*)(ws + WS_DESC);
    int*   sorted = (int*)(ws + WS_SORTED);
    int*   posOf  = (int*)(ws + WS_POSOF);
    float* res    = (float*)(ws + WS_RES);

    hist_k<<<NB, 256, 0, stream>>>(pid, h);
    scan_k<<<1, 256, 0, stream>>>(h, base, desc, ntot);
    scatter_k<<<NB, 256, 0, stream>>>(pid, base, sorted, posOf);

    main_k<<<2 * MAXDESC, 256, 0, stream>>>(OT, W, sorted, desc, ntot, res);

    combine_k<<<dim3((VV + 255) / 256, BB), 256, 0, stream>>>(res, posOf, bias, out);
}